// Round 10
// baseline (178.104 us; speedup 1.0000x reference)
//
#include <hip/hip_runtime.h>

// VectorQuantizer: x [16,1024,256] f32, E [8192,256] f32.
// Outputs concat: quantized_st (4194304 f32) | loss (1) | perplexity (1).
//
// Round 10: GEMM-ized K-loop.
// r3-r9 invariant: ~1800 cyc per 16-code group per wave-slot at any dtype /
// prefetch depth / occupancy -> the per-wave VGPR B-load path is stuck at
// ~9 B/cyc/CU. Switch to the m97 path: global_load_lds (16B) double-buffered
// LDS staging (21 B/cyc/CU proven) + ds_read_b128 fragments, and cut per-CU
// unique B-traffic 4x via 256 rows/block (waves split rows; A-frags 64 VGPRs)
// x split-K 8 (grid 512 = 2 blocks/CU, 0.5 MB B per CU). en_int staged to
// LDS at prologue -> zero global loads inside the K-loop. Partials ->
// best64[8][N] (exact-int orderable u64, ascending code ranges => u64-min
// tie-break = lowest index); r7-proven ticket-fused gather/loss/hist/final.

#define VQ_N 16384
#define VQ_D 256
#define VQ_K 8192

typedef __attribute__((ext_vector_type(4))) int i32x4;

#define SX 22.0f
#define SEF 1040384.0f               // 127 * 8192
#define ENSCALE 11444224.0           // SX * SEF / 2

__device__ inline int q8(float f, float scale) {
  return __float2int_rn(fminf(fmaxf(f * scale, -127.f), 127.f));
}

__device__ inline void gl_lds16(const void* g, void* l) {
  __builtin_amdgcn_global_load_lds(
      (const __attribute__((address_space(1))) unsigned int*)g,
      (__attribute__((address_space(3))) unsigned int*)l, 16, 0, 0);
}
__device__ inline void gl_lds4(const void* g, void* l) {
  __builtin_amdgcn_global_load_lds(
      (const __attribute__((address_space(1))) unsigned int*)g,
      (__attribute__((address_space(3))) unsigned int*)l, 4, 0, 0);
}

// ---- pack E -> i8 swizzled + en_int + zero hist/ticket/loss ----
// B layout: group g (16 codes): off = g*4096 + kchunk*256 + code_local*16 + j,
// k = kchunk*16 + j. Pack thread = (code, kchunk).
__global__ __launch_bounds__(256) void vq_pack(
    const float* __restrict__ E, signed char* __restrict__ Ebs,
    int* __restrict__ en_int, double* __restrict__ loss_sum,
    int* __restrict__ hist, unsigned int* __restrict__ ticket) {
  const int gid = blockIdx.x * 256 + threadIdx.x;  // 0..131071
  if (gid < VQ_K) hist[gid] = 0;
  if (gid == 0) { *loss_sum = 0.0; *ticket = 0u; }
  const int code = gid >> 4;
  const int chunk = gid & 15;
  const float* src = E + (size_t)code * VQ_D + chunk * 16;
  double s = 0.0;
  unsigned int w[4];
#pragma unroll
  for (int v = 0; v < 4; ++v) {
    const float4 f = *(const float4*)(src + v * 4);
    s += (double)f.x * f.x + (double)f.y * f.y + (double)f.z * f.z +
         (double)f.w * f.w;
    const int q0 = q8(f.x, SEF), q1 = q8(f.y, SEF);
    const int q2 = q8(f.z, SEF), q3 = q8(f.w, SEF);
    w[v] = (unsigned)(q0 & 255) | ((unsigned)(q1 & 255) << 8) |
           ((unsigned)(q2 & 255) << 16) | ((unsigned)(q3 & 255) << 24);
  }
  const size_t off =
      ((size_t)(code >> 4) * 16 + chunk) * 256 + (size_t)(code & 15) * 16;
  *(uint4*)(Ebs + off) = make_uint4(w[0], w[1], w[2], w[3]);
#pragma unroll
  for (int m = 1; m <= 8; m <<= 1) s += __shfl_xor(s, m, 64);
  if (chunk == 0) en_int[code] = (int)__double2int_rn(s * ENSCALE);
}

// ---- i8 MFMA score + partial argmin, LDS-staged B (m97 pattern) ----
// Grid 512 x 256. Block (rowblk = b>>3, q = b&7): 256 rows x 1024 codes.
// Waves split rows (64 each); all waves share the staged B chunk (64 codes).
__global__ __launch_bounds__(256, 2) void vq_score(
    const float* __restrict__ X, const signed char* __restrict__ Ebs,
    const int* __restrict__ en_int, unsigned long long* __restrict__ best64) {
  __shared__ __align__(16) signed char bbuf[2][16384];  // 2 x 64-code chunks
  __shared__ __align__(16) int enl[1024];               // en_int for the 8th

  const int tid = threadIdx.x;
  const int wave = tid >> 6;
  const int lane = tid & 63;
  const int quad = lane >> 4;
  const int c15 = lane & 15;
  const int rowblk = blockIdx.x >> 3;
  const int q = blockIdx.x & 7;
  const int r0 = rowblk * 256;
  const int qcode = q * 1024;
  const signed char* ebase = Ebs + (size_t)qcode * 256;

  // Stage en (4 KB) + first B chunk (16 KB). Dest = wave-uniform + lane*size.
  {
    const int* ens = en_int + qcode + wave * 64 + lane;
#pragma unroll
    for (int j = 0; j < 4; ++j)
      gl_lds4(ens + j * 256, enl + j * 256 + wave * 64);
    const signed char* bs = ebase + wave * 1024 + lane * 16;
#pragma unroll
    for (int j = 0; j < 4; ++j)
      gl_lds16(bs + j * 4096, &bbuf[0][j * 4096 + wave * 1024]);
  }

  // A fragments: af[t][m], row r0 + wave*64 + t*16 + c15, k = m*64+quad*16+j.
  i32x4 af[4][4];
#pragma unroll
  for (int t = 0; t < 4; ++t) {
    const float* xr =
        X + (size_t)(r0 + wave * 64 + t * 16 + c15) * VQ_D + quad * 16;
#pragma unroll
    for (int m = 0; m < 4; ++m) {
      const float* p = xr + m * 64;
      i32x4 pk;
#pragma unroll
      for (int v = 0; v < 4; ++v) {
        const float4 f = *(const float4*)(p + v * 4);
        pk[v] = (q8(f.x, SX) & 255) | ((q8(f.y, SX) & 255) << 8) |
                ((q8(f.z, SX) & 255) << 16) | ((q8(f.w, SX) & 255) << 24);
      }
      af[t][m] = pk;
    }
  }

  int best_s[4][4];
  int best_i[4][4];
#pragma unroll
  for (int t = 0; t < 4; ++t)
#pragma unroll
    for (int r = 0; r < 4; ++r) { best_s[t][r] = 0x7fffffff; best_i[t][r] = 0; }

#pragma unroll 1
  for (int c = 0; c < 16; ++c) {
    __syncthreads();  // chunk c staged; prior reads of the other buffer done
    if (c + 1 < 16) {
      const signed char* bs =
          ebase + (c + 1) * 16384 + wave * 1024 + lane * 16;
#pragma unroll
      for (int j = 0; j < 4; ++j)
        gl_lds16(bs + j * 4096, &bbuf[(c + 1) & 1][j * 4096 + wave * 1024]);
    }
    const signed char* cb = &bbuf[c & 1][0];
#pragma unroll
    for (int g = 0; g < 4; ++g) {
      i32x4 bfr[4];
#pragma unroll
      for (int m = 0; m < 4; ++m)
        bfr[m] = *(const i32x4*)(cb + g * 4096 + m * 1024 + lane * 16);
      const int en = enl[(c * 4 + g) * 16 + c15];
      i32x4 a0 = {0, 0, 0, 0}, a1 = {0, 0, 0, 0};
      i32x4 a2 = {0, 0, 0, 0}, a3 = {0, 0, 0, 0};
#pragma unroll
      for (int m = 0; m < 4; ++m) {
        a0 = __builtin_amdgcn_mfma_i32_16x16x64_i8(af[0][m], bfr[m], a0, 0, 0, 0);
        a1 = __builtin_amdgcn_mfma_i32_16x16x64_i8(af[1][m], bfr[m], a1, 0, 0, 0);
        a2 = __builtin_amdgcn_mfma_i32_16x16x64_i8(af[2][m], bfr[m], a2, 0, 0, 0);
        a3 = __builtin_amdgcn_mfma_i32_16x16x64_i8(af[3][m], bfr[m], a3, 0, 0, 0);
      }
      const int code = qcode + (c * 4 + g) * 16 + c15;
#pragma unroll
      for (int r = 0; r < 4; ++r) {
        int s;
        s = en - a0[r];
        if (s < best_s[0][r]) { best_s[0][r] = s; best_i[0][r] = code; }
        s = en - a1[r];
        if (s < best_s[1][r]) { best_s[1][r] = s; best_i[1][r] = code; }
        s = en - a2[r];
        if (s < best_s[2][r]) { best_s[2][r] = s; best_i[2][r] = code; }
        s = en - a3[r];
        if (s < best_s[3][r]) { best_s[3][r] = s; best_i[3][r] = code; }
      }
    }
  }

  // reduce over the 16 code-lanes (exact ints; lowest index on ties)
#pragma unroll
  for (int t = 0; t < 4; ++t)
#pragma unroll
    for (int r = 0; r < 4; ++r) {
      int s = best_s[t][r];
      int i = best_i[t][r];
#pragma unroll
      for (int m = 1; m <= 8; m <<= 1) {
        const int os = __shfl_xor(s, m, 64);
        const int oi = __shfl_xor(i, m, 64);
        if (os < s || (os == s && oi < i)) { s = os; i = oi; }
      }
      if (c15 == 0) {
        const int row = r0 + wave * 64 + t * 16 + quad * 4 + r;
        best64[(size_t)q * VQ_N + row] =
            ((unsigned long long)((unsigned)s ^ 0x80000000u) << 32) |
            (unsigned)i;
      }
    }
}

// ---- gather + loss + hist + (last block) finalize; merges 8 partials ----
__global__ __launch_bounds__(256) void vq_gather_fin(
    const float* __restrict__ X, const float* __restrict__ E,
    const unsigned long long* __restrict__ best64, float* __restrict__ outq,
    double* __restrict__ loss_sum, int* __restrict__ hist,
    unsigned int* __restrict__ ticket, float* __restrict__ out) {
  __shared__ double wsum[4];
  __shared__ double part[256];
  __shared__ int sdone;
  const int wid = threadIdx.x >> 6;
  const int lane = threadIdx.x & 63;
  const int gw = blockIdx.x * 4 + wid;  // 0..2047
  double acc = 0.0;
#pragma unroll 4
  for (int row = gw; row < VQ_N; row += 2048) {
    unsigned long long v =
        (lane < 8) ? best64[(size_t)lane * VQ_N + row] : ~0ULL;
#pragma unroll
    for (int m = 1; m <= 4; m <<= 1) {
      const unsigned long long ov = __shfl_xor(v, m, 64);
      if (ov < v) v = ov;
    }
    v = __shfl(v, 0, 64);
    const int k = (int)(v & 0xFFFFFFFFu);
    if (lane == 0)
      __hip_atomic_fetch_add(&hist[k], 1, __ATOMIC_RELAXED,
                             __HIP_MEMORY_SCOPE_AGENT);
    const float4 qv = *(const float4*)(E + (size_t)k * VQ_D + lane * 4);
    const float4 xv = *(const float4*)(X + (size_t)row * VQ_D + lane * 4);
    *(float4*)(outq + (size_t)row * VQ_D + lane * 4) = qv;
    const double dx = (double)qv.x - xv.x, dy = (double)qv.y - xv.y;
    const double dz = (double)qv.z - xv.z, dw = (double)qv.w - xv.w;
    acc += dx * dx + dy * dy + dz * dz + dw * dw;
  }
#pragma unroll
  for (int off = 32; off > 0; off >>= 1) acc += __shfl_down(acc, off, 64);
  if (lane == 0) wsum[wid] = acc;
  __syncthreads();
  if (threadIdx.x == 0) {
    atomicAdd(loss_sum, wsum[0] + wsum[1] + wsum[2] + wsum[3]);
    __threadfence();
    const unsigned int old = __hip_atomic_fetch_add(
        ticket, 1u, __ATOMIC_ACQ_REL, __HIP_MEMORY_SCOPE_AGENT);
    sdone = (old == 511u) ? 1 : 0;
  }
  __syncthreads();

  if (sdone) {  // last block: all hist/loss atomics are visible
    const int tx = threadIdx.x;
    double s = 0.0;
    for (int k = tx; k < VQ_K; k += 256) {
      const int c = __hip_atomic_load(&hist[k], __ATOMIC_RELAXED,
                                      __HIP_MEMORY_SCOPE_AGENT);
      if (c > 0) {
        const double pr = (double)c * (1.0 / (double)VQ_N);
        s += pr * log(pr + 1e-10);
      }
    }
    part[tx] = s;
    __syncthreads();
    for (int off = 128; off > 0; off >>= 1) {
      if (tx < off) part[tx] += part[tx + off];
      __syncthreads();
    }
    if (tx == 0) {
      const double ls = __hip_atomic_load(loss_sum, __ATOMIC_RELAXED,
                                          __HIP_MEMORY_SCOPE_AGENT);
      out[(size_t)VQ_N * VQ_D] =
          (float)(1.25 * ls / ((double)VQ_N * (double)VQ_D));
      out[(size_t)VQ_N * VQ_D + 1] = (float)exp(-part[0]);
    }
  }
}

extern "C" void kernel_launch(void* const* d_in, const int* in_sizes, int n_in,
                              void* d_out, int out_size, void* d_ws,
                              size_t ws_size, hipStream_t stream) {
  const float* X = (const float*)d_in[0];
  const float* E = (const float*)d_in[1];
  float* out = (float*)d_out;

  char* ws = (char*)d_ws;
  signed char* Ebs = (signed char*)ws;                   // 2 MB
  int* en_int = (int*)(ws + 2097152);                    // 32 KB
  double* loss_sum = (double*)(ws + 2129920);            // 64 B
  int* hist = (int*)(ws + 2129984);                      // 32 KB
  unsigned int* ticket = (unsigned int*)(ws + 2162752);  // 64 B
  unsigned long long* best64 =
      (unsigned long long*)(ws + 2162816);               // 1 MB (8 x N)

  vq_pack<<<512, 256, 0, stream>>>(E, Ebs, en_int, loss_sum, hist, ticket);
  vq_score<<<512, 256, 0, stream>>>(X, Ebs, en_int, best64);
  vq_gather_fin<<<512, 256, 0, stream>>>(X, E, best64, out, loss_sum, hist,
                                         ticket, out);
}